// Round 1
// baseline (686.251 us; speedup 1.0000x reference)
//
#include <hip/hip_runtime.h>

// ---------------------------------------------------------------------------
// Segment-mean over contiguous segments, two-kernel version.
//   in[0]: node_feats  (N_TOTAL=524288, D=256) float32   -- 512 MB, read once
//   in[1]: n_nodes     (B=4096) int32, sums to N_TOTAL
//   out  : graph_feats (B, D) float32                    -- 4 MB
//
// Kernel 1 (one block): exclusive prefix-sum of n_nodes -> d_ws (B ints).
// Kernel 2: one wave per graph; lane i owns columns [4i,4i+4) as a float4
//   accumulator. Explicit 8-row double-buffer keeps >=8 global loads in
//   flight per wave. PLAIN (cached) loads this round -- A/B vs nontemporal:
//   the 6.29 TB/s measured ceiling was with plain float4 loads.
// ---------------------------------------------------------------------------

#define BLOCK 256
#define GPB 4  // graphs per block (= waves per block)

typedef float f4 __attribute__((ext_vector_type(4)));

// ---- kernel 1: exclusive prefix sum of n_nodes into offs (single block) ----
__global__ __launch_bounds__(BLOCK) void seg_offsets(
    const int* __restrict__ n_nodes, int* __restrict__ offs, int b) {
  __shared__ int part[BLOCK];
  const int t = threadIdx.x;
  const int vpt = (b + BLOCK - 1) / BLOCK;
  const int lo = t * vpt;
  const int hi = min(b, lo + vpt);

  int s = 0;
  for (int i = lo; i < hi; ++i) s += n_nodes[i];
  part[t] = s;
  __syncthreads();

  // Hillis-Steele inclusive scan over the 256 partials.
  for (int d = 1; d < BLOCK; d <<= 1) {
    int v = (t >= d) ? part[t - d] : 0;
    __syncthreads();
    part[t] += v;
    __syncthreads();
  }

  int base = (t == 0) ? 0 : part[t - 1];
  for (int i = lo; i < hi; ++i) {
    offs[i] = base;
    base += n_nodes[i];
  }
}

// ---- kernel 2: one wave per graph, pipelined dense column reduction ----
__global__ __launch_bounds__(BLOCK) void seg_mean(
    const float* __restrict__ feats,
    const int* __restrict__ n_nodes,
    const int* __restrict__ offs,
    float* __restrict__ out, int b) {
  const int t = threadIdx.x;
  const int wave = t >> 6;
  const int lane = t & 63;
  const int g = blockIdx.x * GPB + wave;
  if (g >= b) return;

  const int n = n_nodes[g];
  const int start = offs[g];

  // Row-major f4 view: row r of this graph begins at f4 index (start+r)*64.
  const f4* __restrict__ src =
      reinterpret_cast<const f4*>(feats) + (size_t)start * 64 + lane;

  f4 acc[8];
#pragma unroll
  for (int i = 0; i < 8; ++i) acc[i] = (f4)0.0f;

  int r = 0;
  if (n >= 16) {
    // software pipeline: buf holds rows [r-8, r); nb prefetches [r, r+8)
    f4 buf[8];
#pragma unroll
    for (int i = 0; i < 8; ++i) buf[i] = src[(size_t)i * 64];

    for (r = 8; r + 8 <= n; r += 8) {
      f4 nb[8];
#pragma unroll
      for (int i = 0; i < 8; ++i) nb[i] = src[(size_t)(r + i) * 64];
#pragma unroll
      for (int i = 0; i < 8; ++i) acc[i] += buf[i];
#pragma unroll
      for (int i = 0; i < 8; ++i) buf[i] = nb[i];
    }
#pragma unroll
    for (int i = 0; i < 8; ++i) acc[i] += buf[i];
  }
  // tail rows [r, n)
  for (; r < n; ++r) acc[0] += src[(size_t)r * 64];

  f4 total = ((acc[0] + acc[1]) + (acc[2] + acc[3])) +
             ((acc[4] + acc[5]) + (acc[6] + acc[7]));
  total *= (1.0f / (float)n);

  reinterpret_cast<f4*>(out)[(size_t)g * 64 + lane] = total;
}

extern "C" void kernel_launch(void* const* d_in, const int* in_sizes, int n_in,
                              void* d_out, int out_size, void* d_ws, size_t ws_size,
                              hipStream_t stream) {
  const float* node_feats = (const float*)d_in[0];
  const int* n_nodes = (const int*)d_in[1];
  float* out = (float*)d_out;
  int* offs = (int*)d_ws;  // B ints of workspace

  const int b = in_sizes[1];  // 4096 graphs

  seg_offsets<<<1, BLOCK, 0, stream>>>(n_nodes, offs, b);
  seg_mean<<<(b + GPB - 1) / GPB, BLOCK, 0, stream>>>(node_feats, n_nodes, offs,
                                                      out, b);
}

// Round 2
// 674.360 us; speedup vs baseline: 1.0176x; 1.0176x over previous
//
#include <hip/hip_runtime.h>

// ---------------------------------------------------------------------------
// Segment-mean over contiguous segments, compact-window version.
//   in[0]: node_feats  (N_TOTAL=524288, D=256) float32   -- 512 MB, read once
//   in[1]: n_nodes     (B=4096) int32, sums to N_TOTAL
//   out  : graph_feats (B, D) float32                    -- 4 MB
//
// Theory: the old one-wave-per-graph layout ran 4096 concurrent HBM streams
// scattered over 512 MB -> row-buffer thrash -> ~1.65 TB/s. Here one
// 1024-thread block owns 16 consecutive graphs (~2 MB contiguous) and its 16
// waves interleave at ROW granularity (wave v reads rows == v mod 16), so the
// block advances a single compact window. 256 blocks = 256 streams chip-wide.
// Cross-wave per-graph partials combine via LDS ds_add_f32 (conflict-free
// plane layout). Nontemporal loads (read-once) kept -- they beat plain loads
// by ~40 us in the round-0/1 A/B.
// ---------------------------------------------------------------------------

#define BLOCK 1024
#define WAVES 16  // waves per block
#define GPB 16    // graphs per block
#define NGP1 (GPB + 1)

typedef float f4 __attribute__((ext_vector_type(4)));

// ---- kernel 1: exclusive prefix sum of n_nodes into offs[0..b] ----
__global__ __launch_bounds__(256) void seg_offsets(
    const int* __restrict__ n_nodes, int* __restrict__ offs, int b) {
  __shared__ int part[256];
  const int t = threadIdx.x;
  const int vpt = (b + 255) / 256;
  const int lo = t * vpt;
  const int hi = min(b, lo + vpt);

  int s = 0;
  for (int i = lo; i < hi; ++i) s += n_nodes[i];
  part[t] = s;
  __syncthreads();

  for (int d = 1; d < 256; d <<= 1) {
    int v = (t >= d) ? part[t - d] : 0;
    __syncthreads();
    part[t] += v;
    __syncthreads();
  }

  int base = (t == 0) ? 0 : part[t - 1];
  for (int i = lo; i < hi; ++i) {
    offs[i] = base;
    base += n_nodes[i];
  }
  if (hi == b && lo < hi) offs[b] = base;  // total
}

// ---- kernel 2: 16 graphs per block, row-interleaved waves ----
__global__ __launch_bounds__(BLOCK, 1) void seg_mean(
    const float* __restrict__ feats,
    const int* __restrict__ offs,
    float* __restrict__ out, int b) {
  // [component][graph][lane]: float index = c*GPB*64 + gl*64 + lane
  // -> lane stride 1 word -> 2 lanes/bank -> conflict-free (m136).
  __shared__ float lacc[4][GPB][64];
  __shared__ int loff[NGP1];

  const int t = threadIdx.x;
  const int wave = t >> 6;
  const int lane = t & 63;
  const int g0 = blockIdx.x * GPB;

  for (int i = t; i < 4 * GPB * 64; i += BLOCK) ((float*)lacc)[i] = 0.0f;
  if (t < NGP1) loff[t] = offs[min(g0 + t, b)];
  __syncthreads();

  const int S = loff[0];
  const f4* __restrict__ srcb = reinterpret_cast<const f4*>(feats);

  for (int gl = 0; gl < GPB; ++gl) {
    const int lo = loff[gl], hi = loff[gl + 1];
    // first row of this graph with (row - S) % WAVES == wave
    const int rem = (lo - S) & (WAVES - 1);
    const int r0 = lo + ((wave - rem) & (WAVES - 1));

    f4 acc = (f4)0.0f;
#pragma unroll 8
    for (int r = r0; r < hi; r += WAVES) {
      acc += __builtin_nontemporal_load(&srcb[(size_t)r * 64 + lane]);
    }
    // conflict-free LDS planes; 16 waves race per address -> ds_add_f32
    atomicAdd(&lacc[0][gl][lane], acc.x);
    atomicAdd(&lacc[1][gl][lane], acc.y);
    atomicAdd(&lacc[2][gl][lane], acc.z);
    atomicAdd(&lacc[3][gl][lane], acc.w);
  }
  __syncthreads();

  // wave v writes graph v
  const int g = g0 + wave;
  if (g < b) {
    const int n = loff[wave + 1] - loff[wave];
    f4 tot;
    tot.x = lacc[0][wave][lane];
    tot.y = lacc[1][wave][lane];
    tot.z = lacc[2][wave][lane];
    tot.w = lacc[3][wave][lane];
    tot *= (1.0f / (float)n);
    reinterpret_cast<f4*>(out)[(size_t)g * 64 + lane] = tot;
  }
}

extern "C" void kernel_launch(void* const* d_in, const int* in_sizes, int n_in,
                              void* d_out, int out_size, void* d_ws, size_t ws_size,
                              hipStream_t stream) {
  const float* node_feats = (const float*)d_in[0];
  const int* n_nodes = (const int*)d_in[1];
  float* out = (float*)d_out;
  int* offs = (int*)d_ws;  // B+1 ints of workspace

  const int b = in_sizes[1];  // 4096 graphs

  seg_offsets<<<1, 256, 0, stream>>>(n_nodes, offs, b);
  seg_mean<<<(b + GPB - 1) / GPB, BLOCK, 0, stream>>>(node_feats, offs, out, b);
}